// Round 4
// baseline (10632.529 us; speedup 1.0000x reference)
//
#include <hip/hip_runtime.h>

#define Hdim 64
#define Tlen 16384
#define Bsz  16
#define LOG2E 1.44269504088896340736f

// readlane: broadcast lane l's value of v to an SGPR (uniform)
__device__ __forceinline__ float rlane(float v, int l) {
    return __int_as_float(__builtin_amdgcn_readlane(__float_as_int(v), l));
}

// sigmoid(x) = 1/(1+2^(-x*log2e))   : v_mul, v_exp, v_add, v_rcp
__device__ __forceinline__ float sigm(float x) {
    return __builtin_amdgcn_rcpf(1.0f + __builtin_amdgcn_exp2f(-LOG2E * x));
}
// tanh(x) = 1 - 2/(2^(2x*log2e)+1)  : saturates correctly at +/-1
__device__ __forceinline__ float tanhfast(float x) {
    const float e = __builtin_amdgcn_exp2f((2.0f * LOG2E) * x);
    return fmaf(-2.0f, __builtin_amdgcn_rcpf(e + 1.0f), 1.0f);
}

__global__ void __launch_bounds__(256, 1)
apdl_rnn_kernel(const float* __restrict__ x,
                const float* __restrict__ W_ih,
                const float* __restrict__ W_hh,
                const float* __restrict__ b_ih,
                const float* __restrict__ b_hh,
                float* __restrict__ out)
{
    const int b    = blockIdx.x;   // batch element
    const int tid  = threadIdx.x;  // 0..255 == gate-row index
    const int wid  = tid >> 6;     // wave id: 0=i, 1=f, 2=g, 3=o gates
    const int lane = tid & 63;     // j index within hidden dim

    // W_hh row for this gate, held in VGPRs for the whole kernel.
    float w[Hdim];
    #pragma unroll
    for (int k = 0; k < Hdim; k += 4) {
        const float4 v = *reinterpret_cast<const float4*>(&W_hh[tid * Hdim + k]);
        w[k] = v.x; w[k + 1] = v.y; w[k + 2] = v.z; w[k + 3] = v.w;
    }
    const float bias = b_ih[tid] + b_hh[tid];
    const float wih  = W_ih[tid];          // I == 1

    // ap_coeff = (1-alpha)/(1+alpha), alpha = 48000/44100-1  ->  exactly 0.8375
    const float apc = 0.8375f;

    // State, replicated per wave; lane j holds index j of each vector.
    float ap_h = 0.f, ap_c = 0.f;          // allpass output (LSTM h,c input)
    float h1 = 0.f, c1 = 0.f;              // hc_{t-1}
    float h2 = 0.f, c2 = 0.f;              // hc_{t-2}

    __shared__ float gbuf[2][256];         // double-buffered activated gates
    __shared__ float apbuf[4][Hdim];       // per-wave private h-broadcast buf

    const float* xb = x + (size_t)b * Tlen;
    float xnext = xb[lane];                // prefetch first 64 timesteps
    float xcur  = 0.f;

    float* yp = out + (size_t)b * Tlen * Hdim + lane;
    float* cp = out + (size_t)Bsz * Tlen * Hdim + (size_t)b * Tlen * Hdim + lane;

    float* apw = &apbuf[wid][0];

    for (int t = 0; t < Tlen; ++t) {
        // PIN the weight row INSIDE the loop: iteration t's pin consumes
        // iteration t-1's pin output (a loop phi of an asm def -> not
        // rematerializable), forcing w[] to stay resident in VGPRs across
        // the backedge. Emits zero instructions. The pre-loop pin variant
        // (round 3) failed: RA split the range and re-loaded from global
        // every step (VGPR_Count=52 proved w was never resident).
        #pragma unroll
        for (int k = 0; k < Hdim; k += 4) {
            asm volatile("" : "+v"(w[k]), "+v"(w[k+1]), "+v"(w[k+2]), "+v"(w[k+3]));
        }

        if ((t & 63) == 0) {               // uniform branch, once per 64 steps
            xcur = xnext;
            if (t + 64 < Tlen) xnext = xb[t + 64 + lane];
        }
        const float xt = rlane(xcur, t & 63);

        // allpass filter: ap_t = apc*(hc_{t-1} - ap_{t-1}) + hc_{t-2}
        ap_h = fmaf(apc, h1 - ap_h, h2);
        ap_c = fmaf(apc, c1 - ap_c, c2);

        // Broadcast ap_h across the wave through this wave's private LDS
        // buffer: 1 ds_write + 16 uniform-address ds_read_b128 (broadcast,
        // conflict-free, same-wave RAW -> no barrier needed).
        apw[lane] = ap_h;

        float a0 = fmaf(xt, wih, bias);
        float a1 = 0.f, a2 = 0.f, a3 = 0.f;
        const float4* hp = reinterpret_cast<const float4*>(apw);
        #pragma unroll
        for (int k4 = 0; k4 < Hdim / 4; ++k4) {
            const float4 hv = hp[k4];
            a0 = fmaf(hv.x, w[4 * k4    ], a0);
            a1 = fmaf(hv.y, w[4 * k4 + 1], a1);
            a2 = fmaf(hv.z, w[4 * k4 + 2], a2);
            a3 = fmaf(hv.w, w[4 * k4 + 3], a3);
        }
        const float gate = (a0 + a1) + (a2 + a3);

        // activation: wave-uniform branch (wave 2 = cell gate = tanh)
        float act;
        if (wid == 2) act = tanhfast(gate);
        else          act = sigm(gate);

        gbuf[t & 1][tid] = act;
        __syncthreads();                   // single barrier per step (dbuf'd)

        const float* gb = gbuf[t & 1];
        const float ig = gb[lane];
        const float fg = gb[64  + lane];
        const float gg = gb[128 + lane];
        const float og = gb[192 + lane];

        // epilogue, redundantly on all 4 waves to keep state replicated
        const float cn = fmaf(fg, ap_c, ig * gg);
        const float hn = og * tanhfast(cn);

        h2 = h1; c2 = c1; h1 = hn; c1 = cn;

        if      (wid == 0) *yp = hn;       // y output
        else if (wid == 1) *cp = cn;       // c output
        yp += Hdim; cp += Hdim;
    }

    // ap_final: the ap used as input to the last cell (B, 2H)
    if (wid == 0) {
        float* ap_out = out + 2 * (size_t)Bsz * Tlen * Hdim + (size_t)b * 2 * Hdim;
        ap_out[lane]        = ap_h;
        ap_out[Hdim + lane] = ap_c;
    }
}

extern "C" void kernel_launch(void* const* d_in, const int* in_sizes, int n_in,
                              void* d_out, int out_size, void* d_ws, size_t ws_size,
                              hipStream_t stream) {
    const float* x    = (const float*)d_in[0];
    const float* W_ih = (const float*)d_in[1];
    const float* W_hh = (const float*)d_in[2];
    const float* b_ih = (const float*)d_in[3];
    const float* b_hh = (const float*)d_in[4];
    float* out = (float*)d_out;

    apdl_rnn_kernel<<<dim3(Bsz), dim3(256), 0, stream>>>(x, W_ih, W_hh, b_ih, b_hh, out);
}

// Round 5
// 8994.222 us; speedup vs baseline: 1.1822x; 1.1822x over previous
//
#include <hip/hip_runtime.h>

#define Hdim 64
#define Tlen 16384
#define Bsz  16
#define LOG2E 1.44269504088896340736f

// readlane: broadcast lane l's value of v to an SGPR (uniform)
__device__ __forceinline__ float rlane(float v, int l) {
    return __int_as_float(__builtin_amdgcn_readlane(__float_as_int(v), l));
}

// sigmoid(x) = 1/(1+2^(-x*log2e))   : v_mul, v_exp, v_add, v_rcp
__device__ __forceinline__ float sigm(float x) {
    return __builtin_amdgcn_rcpf(1.0f + __builtin_amdgcn_exp2f(-LOG2E * x));
}
// tanh(x) = 1 - 2/(2^(2x*log2e)+1)  : saturates correctly at +/-1
__device__ __forceinline__ float tanhfast(float x) {
    const float e = __builtin_amdgcn_exp2f((2.0f * LOG2E) * x);
    return fmaf(-2.0f, __builtin_amdgcn_rcpf(e + 1.0f), 1.0f);
}

__global__ void __launch_bounds__(256, 1)
apdl_rnn_kernel(const float* __restrict__ x,
                const float* __restrict__ W_ih,
                const float* __restrict__ W_hh,
                const float* __restrict__ b_ih,
                const float* __restrict__ b_hh,
                float* out)   // NOTE: no __restrict__ — see laundering comment
{
    const int b    = blockIdx.x;   // batch element
    const int tid  = threadIdx.x;  // 0..255 == gate-row index
    const int wid  = tid >> 6;     // wave id: 0=i, 1=f, 2=g, 3=o gates
    const int lane = tid & 63;     // j index within hidden dim

    // W_hh row for this gate, held in VGPRs for the whole kernel.
    //
    // Residency trick (rounds 3/4 post-mortem): the compiler rematerialized
    // these loads inside the t-loop (round 3, VGPR=52) or spilled the array
    // to scratch when remat was blocked by an in-loop pin (round 4, VGPR=48,
    // +1.3ms pure stall).  Remat was legal because the loads were provably
    // invariant.  So: launder the pointer through opaque asm (provenance
    // unknown) and store through a non-restrict `out` inside the loop ->
    // re-executing the loads in the loop would be ILLEGAL (may-alias), the
    // values must stay live in registers, and at launch_bounds(256,1) there
    // is no pressure reason to spill ~110 VGPRs.
    const float* wp = W_hh + (size_t)tid * Hdim;
    asm volatile("" : "+v"(wp));           // opaque: kills invariance proof

    float w[Hdim];
    #pragma unroll
    for (int k = 0; k < Hdim; k += 4) {
        const float4 v = *reinterpret_cast<const float4*>(wp + k);
        w[k] = v.x; w[k + 1] = v.y; w[k + 2] = v.z; w[k + 3] = v.w;
    }
    float bias = b_ih[tid] + b_hh[tid];
    float wih  = W_ih[tid];                // I == 1
    asm volatile("" : "+v"(bias), "+v"(wih));

    // ap_coeff = (1-alpha)/(1+alpha), alpha = 48000/44100-1  ->  exactly 0.8375
    const float apc = 0.8375f;

    // State, replicated per wave; lane j holds index j of each vector.
    float ap_h = 0.f, ap_c = 0.f;          // allpass output (LSTM h,c input)
    float h1 = 0.f, c1 = 0.f;              // hc_{t-1}
    float h2 = 0.f, c2 = 0.f;              // hc_{t-2}

    __shared__ float gbuf[2][256];         // double-buffered activated gates
    __shared__ float apbuf[4][Hdim];       // per-wave private h-broadcast buf

    const float* xb = x + (size_t)b * Tlen;
    float xnext = xb[lane];                // prefetch first 64 timesteps
    float xcur  = 0.f;

    float* yp = out + (size_t)b * Tlen * Hdim + lane;
    float* cp = out + (size_t)Bsz * Tlen * Hdim + (size_t)b * Tlen * Hdim + lane;

    float* apw = &apbuf[wid][0];

    for (int t = 0; t < Tlen; ++t) {
        if ((t & 63) == 0) {               // uniform branch, once per 64 steps
            xcur = xnext;
            if (t + 64 < Tlen) xnext = xb[t + 64 + lane];
        }
        const float xt = rlane(xcur, t & 63);

        // allpass filter: ap_t = apc*(hc_{t-1} - ap_{t-1}) + hc_{t-2}
        ap_h = fmaf(apc, h1 - ap_h, h2);
        ap_c = fmaf(apc, c1 - ap_c, c2);

        // Broadcast ap_h across the wave through this wave's private LDS
        // buffer: 1 ds_write + 16 uniform-address ds_read_b128 (broadcast,
        // conflict-free, same-wave RAW -> no barrier needed).
        apw[lane] = ap_h;

        float a0 = fmaf(xt, wih, bias);
        float a1 = 0.f, a2 = 0.f, a3 = 0.f;
        const float4* hp = reinterpret_cast<const float4*>(apw);
        #pragma unroll
        for (int k4 = 0; k4 < Hdim / 4; ++k4) {
            const float4 hv = hp[k4];
            a0 = fmaf(hv.x, w[4 * k4    ], a0);
            a1 = fmaf(hv.y, w[4 * k4 + 1], a1);
            a2 = fmaf(hv.z, w[4 * k4 + 2], a2);
            a3 = fmaf(hv.w, w[4 * k4 + 3], a3);
        }
        const float gate = (a0 + a1) + (a2 + a3);

        // activation: wave-uniform branch (wave 2 = cell gate = tanh)
        float act;
        if (wid == 2) act = tanhfast(gate);
        else          act = sigm(gate);

        gbuf[t & 1][tid] = act;
        __syncthreads();                   // single barrier per step (dbuf'd)

        const float* gb = gbuf[t & 1];
        const float ig = gb[lane];
        const float fg = gb[64  + lane];
        const float gg = gb[128 + lane];
        const float og = gb[192 + lane];

        // epilogue, redundantly on all 4 waves to keep state replicated
        const float cn = fmaf(fg, ap_c, ig * gg);
        const float hn = og * tanhfast(cn);

        h2 = h1; c2 = c1; h1 = hn; c1 = cn;

        if      (wid == 0) *yp = hn;       // y output
        else if (wid == 1) *cp = cn;       // c output
        yp += Hdim; cp += Hdim;
    }

    // ap_final: the ap used as input to the last cell (B, 2H)
    if (wid == 0) {
        float* ap_out = out + 2 * (size_t)Bsz * Tlen * Hdim + (size_t)b * 2 * Hdim;
        ap_out[lane]        = ap_h;
        ap_out[Hdim + lane] = ap_c;
    }
}

extern "C" void kernel_launch(void* const* d_in, const int* in_sizes, int n_in,
                              void* d_out, int out_size, void* d_ws, size_t ws_size,
                              hipStream_t stream) {
    const float* x    = (const float*)d_in[0];
    const float* W_ih = (const float*)d_in[1];
    const float* W_hh = (const float*)d_in[2];
    const float* b_ih = (const float*)d_in[3];
    const float* b_hh = (const float*)d_in[4];
    float* out = (float*)d_out;

    apdl_rnn_kernel<<<dim3(Bsz), dim3(256), 0, stream>>>(x, W_ih, W_hh, b_ih, b_hh, out);
}